// Round 22
// baseline (410.081 us; speedup 1.0000x reference)
//
#include <hip/hip_runtime.h>

#define NV   50000
#define NR   5
#define NT   8
#define CIN  64
#define COUT 64
#define BARY (NR*NT*3)      // 120
#define BK_ELEMS (NR*CIN*NT*COUT)   // 163840 fp16 (320 KB) — L2-resident
#define BM2  64
#define NBLK2 ((NV + BM2 - 1) / BM2)   // 782
#define NICC 10             // K-chunks (icc), 32 K-elems each

#define WL_BYTES 262144
#define SIG16_BYTES (NV*CIN*2)                            // 6.4 MB
#define WS_NEED7 (WL_BYTES + 2u*BK_ELEMS + SIG16_BYTES)   // ~7.0 MB

typedef _Float16 f16x8 __attribute__((ext_vector_type(8)));
typedef _Float16 f16x4 __attribute__((ext_vector_type(4)));
typedef float    f32x4 __attribute__((ext_vector_type(4)));

// ---------- K0a: kernel -> fp16 ws with LDS read-swizzle PRE-BAKED ----------
// (round-16/18 verified.) Staging copies bk linearly into Blds; MFMA read uses
// 16B-granule u = gi ^ ((gi>>3)&7) (involution), so sigma is baked here.
__global__ __launch_bounds__(256) void build_bk12(
    const float* __restrict__ kern, _Float16* __restrict__ bk)
{
    int e   = blockIdx.x * 256 + threadIdx.x;
    int h   = e & 7;
    int u   = (e >> 3) & 2047;
    int icc = e >> 14;
    int gi  = u ^ ((u >> 3) & 7);     // involution (bits 3-5 untouched)
    int col = gi >> 2;
    int gq  = gi & 3;
    int i   = icc >> 1;
    int c   = (icc & 1) * 32 + gq * 8 + h;
    int m   = col >> 6;
    int d   = col & 63;
    bk[e] = (_Float16)kern[((i * NT + m) * CIN + c) * COUT + d];
}

// ---------- K0b: signal -> fp16 ----------
__global__ __launch_bounds__(256) void build_sig16(
    const float* __restrict__ signal, _Float16* __restrict__ sig16)
{
    int e = blockIdx.x * 256 + threadIdx.x;
    sig16[e] = (_Float16)signal[e];
}

// ---------- main v17: A-SUPER-tile (all 8 j) staged once per icc ----------
// Inner j-loop is BARRIER-FREE (A and B stable in LDS for whole icc):
// 128 MFMA per barrier pair, 20 barriers total (was 160). Swizzled A+B
// reads (conflict-free) since LDS throughput is now the critical path.
__global__ __launch_bounds__(512, 4) void geo_mfma17(
    const float* __restrict__ bary_w,
    const int*   __restrict__ bary_idx,
    const _Float16* __restrict__ sig16,
    const _Float16* __restrict__ bk,
    float* __restrict__ out,
    int*   __restrict__ wl)
{
    __shared__ __align__(16) _Float16 Blds[16384];      // 32 KB (single buf)
    __shared__ __align__(16) _Float16 Axs[NT][2048];    // 32 KB: slot j, v8-swizzled
    __shared__ float nrm[BM2][NT];                      // 2 KB
    __shared__ int   besti[BM2];

    const int tid  = threadIdx.x;
    const int lane = tid & 63;
    const int wn   = tid >> 6;         // wave wn: owns rotation k=wn; stages slot j=wn
    const int g    = lane >> 4;
    const int l15  = lane & 15;
    const int vbase = blockIdx.x * BM2;
    const bool v_sok = (vbase + lane < NV);   // staging: lane = vertex

    f32x4 acc[4][4];
    {
        f32x4 z = {0.f, 0.f, 0.f, 0.f};
        #pragma unroll
        for (int mf = 0; mf < 4; ++mf)
            #pragma unroll
            for (int nf = 0; nf < 4; ++nf) acc[mf][nf] = z;
    }

    // ---- stage A-super slot wn for chunk icc2: x[v, i(icc2), j=wn, c-half] ----
    auto STAGE_A = [&](int icc2) {
        const int i2 = icc2 >> 1;
        const int ch = (icc2 & 1) * 32;
        float w0, w1, w2; int a0, a1, a2;
        if (v_sok) {
            const int base = (vbase + lane) * BARY + (i2 * NT + wn) * 3;
            w0 = bary_w[base + 0];
            w1 = bary_w[base + 1];
            w2 = bary_w[base + 2];
            a0 = bary_idx[base + 0];
            a1 = bary_idx[base + 1];
            a2 = bary_idx[base + 2];
        } else {
            w0 = w1 = w2 = 0.f;
            a0 = a1 = a2 = 0;
        }
        #pragma unroll 1
        for (int half = 0; half < 2; ++half) {
            const int co = ch + half * 16;
            const f16x8 p0 = *(const f16x8*)(sig16 + a0 * CIN + co);
            const f16x8 p1 = *(const f16x8*)(sig16 + a0 * CIN + co + 8);
            const f16x8 q0 = *(const f16x8*)(sig16 + a1 * CIN + co);
            const f16x8 q1 = *(const f16x8*)(sig16 + a1 * CIN + co + 8);
            const f16x8 r0 = *(const f16x8*)(sig16 + a2 * CIN + co);
            const f16x8 r1 = *(const f16x8*)(sig16 + a2 * CIN + co + 8);
            f16x8 h0, h1;
            #pragma unroll
            for (int e = 0; e < 8; ++e) {
                h0[e] = (_Float16)(w0 * (float)p0[e] + w1 * (float)q0[e] + w2 * (float)r0[e]);
                h1[e] = (_Float16)(w0 * (float)p1[e] + w1 * (float)q1[e] + w2 * (float)r1[e]);
            }
            const int o0 = half * 2, o1 = half * 2 + 1;
            *(f16x8*)&Axs[wn][(o0 * 512 + lane * 8) ^ (o0 << 4)] = h0;   // v8 swizzle
            *(f16x8*)&Axs[wn][(o1 * 512 + lane * 8) ^ (o1 << 4)] = h1;
        }
    };

    // ---- B chunk reg-staging (linear copy; permutation pre-baked in ws) ----
    f16x8 breg0, breg1, breg2, breg3;
    auto BLOADR = [&](int icc2) {
        const _Float16* src = bk + icc2 * 16384 + wn * 2048 + lane * 8;
        breg0 = *(const f16x8*)(src + 0 * 512);
        breg1 = *(const f16x8*)(src + 1 * 512);
        breg2 = *(const f16x8*)(src + 2 * 512);
        breg3 = *(const f16x8*)(src + 3 * 512);
    };
    auto BWRITE = [&]() {
        _Float16* dst = &Blds[wn * 2048 + lane * 8];
        *(f16x8*)(dst + 0 * 512) = breg0;
        *(f16x8*)(dst + 1 * 512) = breg1;
        *(f16x8*)(dst + 2 * 512) = breg2;
        *(f16x8*)(dst + 3 * 512) = breg3;
    };

    // ---- prologue: A-super(0) + B(0) ----
    STAGE_A(0);
    BLOADR(0);
    BWRITE();
    __syncthreads();

    #pragma unroll 1
    for (int icc = 0; icc < NICC; ++icc) {
        const bool more = (icc + 1 < NICC);
        if (more) BLOADR(icc + 1);      // in flight across the whole inner loop

        // ---- inner: 8 j-iterations, 128 MFMA, NO barriers ----
        #pragma unroll 1
        for (int j = 0; j < NT; ++j) {
            const int m = (j + wn) & 7;
            f16x8 afrag[4];
            #pragma unroll
            for (int mf = 0; mf < 4; ++mf)
                afrag[mf] = *(const f16x8*)&Axs[j][(g * 512 + (mf * 16 + l15) * 8) ^ (g << 4)];
            #pragma unroll
            for (int nf = 0; nf < 4; ++nf) {
                const int col = m * 64 + nf * 16 + l15;
                const int gi  = col * 4 + g;
                const int u   = gi ^ ((gi >> 3) & 7);   // matches baked sigma
                const f16x8 bfrag = *(const f16x8*)&Blds[u * 8];
                #pragma unroll
                for (int mf = 0; mf < 4; ++mf)
                    acc[mf][nf] = __builtin_amdgcn_mfma_f32_16x16x32_f16(
                        afrag[mf], bfrag, acc[mf][nf], 0, 0, 0);
            }
        }

        __syncthreads();                // all Axs/Blds reads of icc done
        if (more) {
            BWRITE();                   // waits vmcnt on breg (long arrived)
            STAGE_A(icc + 1);           // gather chain exposed once per icc
        }
        __syncthreads();                // new A/B visible
    }

    // ---- epilogue: wave wn owns rotation wn; norms per row ----
    #pragma unroll
    for (int mf = 0; mf < 4; ++mf)
        #pragma unroll
        for (int ri = 0; ri < 4; ++ri) {
            float s = 0.f;
            #pragma unroll
            for (int nf = 0; nf < 4; ++nf) {
                float vv = acc[mf][nf][ri];
                s = fmaf(vv, vv, s);
            }
            #pragma unroll
            for (int off = 1; off < 16; off <<= 1)
                s += __shfl_xor(s, off);
            if (l15 == 0) nrm[mf * 16 + g * 4 + ri][wn] = s;
        }
    __syncthreads();

    if (tid < BM2) {
        const int v = vbase + tid;
        float bn = nrm[tid][0];
        float sec = -1e30f;
        int best = 0;
        #pragma unroll
        for (int k = 1; k < NT; ++k) {
            float nv = nrm[tid][k];
            if (nv > bn)       { sec = bn; bn = nv; best = k; }
            else if (nv > sec) { sec = nv; }
        }
        // gap-err sigma ~3.6e-3 -> ~8 sigma (validated rounds 14-21, absmax 0.0156)
        const bool flag = (bn - sec) <= (3.0e-2f + 4e-4f * bn);
        besti[tid] = flag ? -1 : best;
        if (flag && v < NV) { int p = atomicAdd(wl, 1); wl[1 + p] = v; }
    }
    __syncthreads();

    #pragma unroll
    for (int mf = 0; mf < 4; ++mf)
        #pragma unroll
        for (int ri = 0; ri < 4; ++ri) {
            const int row = mf * 16 + g * 4 + ri;
            const int v   = vbase + row;
            const int bsel = (v < NV) ? besti[row] : -1;
            if (bsel == wn) {
                #pragma unroll
                for (int nf = 0; nf < 4; ++nf) {
                    const int d = nf * 16 + l15;
                    out[v * COUT + d] = fmaxf(acc[mf][nf][ri], 0.0f);
                }
            }
        }
}

// ---------- parallel fp64 refine: one BLOCK (4 waves) per vertex ----------
__global__ __launch_bounds__(256) void geo_refine_f64p(
    const float* __restrict__ signal,
    const float* __restrict__ bary_w,
    const int*   __restrict__ bary_idx,
    const float* __restrict__ kern,
    float*       __restrict__ out,
    const int*   __restrict__ wl,
    int nall)
{
    __shared__ __align__(16) float xs[NR][CIN][NT];
    __shared__ double part[4][NT][COUT];
    __shared__ double convl[NT][COUT];
    __shared__ double nks[NT];
    __shared__ int bestS;

    const int tid  = threadIdx.x;
    const int wave = tid >> 6;
    const int lane = tid & 63;
    const int count = wl ? wl[0] : nall;

    for (int w = blockIdx.x; w < count; w += gridDim.x) {
        const int v = wl ? wl[1 + w] : w;

        for (int ij = wave; ij < NR * NT; ij += 4) {
            const int i = ij >> 3, j = ij & 7;
            const int base = v * BARY + ij * 3;
            const float w0 = bary_w[base], w1 = bary_w[base+1], w2 = bary_w[base+2];
            const int   i0 = bary_idx[base], i1 = bary_idx[base+1], i2 = bary_idx[base+2];
            xs[i][lane][j] = w0 * signal[i0*CIN + lane]
                           + w1 * signal[i1*CIN + lane]
                           + w2 * signal[i2*CIN + lane];
        }
        __syncthreads();

        double acc[NT];
        #pragma unroll
        for (int k = 0; k < NT; ++k) acc[k] = 0.0;

        for (int r = wave * 80; r < wave * 80 + 80; ++r) {
            const int i = r >> 6, c = r & 63;
            const float4 xa = *reinterpret_cast<const float4*>(&xs[i][c][0]);
            const float4 xb = *reinterpret_cast<const float4*>(&xs[i][c][4]);
            const double x8[NT] = {(double)xa.x, (double)xa.y, (double)xa.z, (double)xa.w,
                                   (double)xb.x, (double)xb.y, (double)xb.z, (double)xb.w};
            #pragma unroll
            for (int mm = 0; mm < NT; ++mm) {
                const double kv = (double)kern[((i * NT + mm) * CIN + c) * COUT + lane];
                #pragma unroll
                for (int k = 0; k < NT; ++k)
                    acc[k] = fma(x8[(mm - k + NT) & (NT - 1)], kv, acc[k]);
            }
        }
        #pragma unroll
        for (int k = 0; k < NT; ++k) part[wave][k][lane] = acc[k];
        __syncthreads();

        for (int kd = tid; kd < NT * COUT; kd += 256) {
            const int k = kd >> 6, d = kd & 63;
            convl[k][d] = ((part[0][k][d] + part[1][k][d])
                         + (part[2][k][d] + part[3][k][d]));
        }
        __syncthreads();

        for (int k = wave; k < NT; k += 4) {
            double n = convl[k][lane] * convl[k][lane];
            #pragma unroll
            for (int off = 32; off >= 1; off >>= 1) n += __shfl_xor(n, off);
            if (lane == 0) nks[k] = n;
        }
        __syncthreads();

        if (tid == 0) {
            int best = 0; double bn = nks[0];
            #pragma unroll
            for (int k = 1; k < NT; ++k)
                if (nks[k] > bn) { bn = nks[k]; best = k; }
            bestS = best;
        }
        __syncthreads();

        if (tid < COUT) out[v * COUT + tid] = fmaxf((float)convl[bestS][tid], 0.0f);
        __syncthreads();
    }
}

extern "C" void kernel_launch(void* const* d_in, const int* in_sizes, int n_in,
                              void* d_out, int out_size, void* d_ws, size_t ws_size,
                              hipStream_t stream) {
    const float* signal   = (const float*)d_in[0];
    const float* bary_w   = (const float*)d_in[1];
    const int*   bary_idx = (const int*)d_in[2];
    const float* kern     = (const float*)d_in[3];
    float* out = (float*)d_out;

    if (ws_size >= (size_t)WS_NEED7) {
        int* wl = (int*)d_ws;
        _Float16* bk    = (_Float16*)((char*)d_ws + WL_BYTES);
        _Float16* sig16 = (_Float16*)((char*)d_ws + WL_BYTES + 2u * BK_ELEMS);
        hipMemsetAsync(wl, 0, sizeof(int), stream);
        build_bk12<<<dim3(BK_ELEMS / 256), dim3(256), 0, stream>>>(kern, bk);
        build_sig16<<<dim3(NV * CIN / 256), dim3(256), 0, stream>>>(signal, sig16);
        geo_mfma17<<<dim3(NBLK2), dim3(512), 0, stream>>>(
            bary_w, bary_idx, sig16, bk, out, wl);
        geo_refine_f64p<<<dim3(1024), dim3(256), 0, stream>>>(
            signal, bary_w, bary_idx, kern, out, wl, 0);
    } else {
        geo_refine_f64p<<<dim3(1024), dim3(256), 0, stream>>>(
            signal, bary_w, bary_idx, kern, out, nullptr, NV);
    }
}

// Round 23
// 327.086 us; speedup vs baseline: 1.2537x; 1.2537x over previous
//
#include <hip/hip_runtime.h>

#define NV   50000
#define NR   5
#define NT   8
#define CIN  64
#define COUT 64
#define BARY (NR*NT*3)      // 120
#define BK_ELEMS (NR*CIN*NT*COUT)   // 163840 fp16 (320 KB) — L2-resident
#define BM2  64
#define NBLK2 ((NV + BM2 - 1) / BM2)   // 782
#define NICC 10             // K-chunks (icc), 32 K-elems each
#define NCH  80             // iterations: icc-OUTER x j-INNER (B reused across j)

#define WL_BYTES 262144
#define SIG16_BYTES (NV*CIN*2)                            // 6.4 MB
#define WS_NEED7 (WL_BYTES + 2u*BK_ELEMS + SIG16_BYTES)   // ~7.0 MB

typedef _Float16 f16x8 __attribute__((ext_vector_type(8)));
typedef _Float16 f16x4 __attribute__((ext_vector_type(4)));
typedef float    f32x4 __attribute__((ext_vector_type(4)));

// ---------- K0a: kernel -> fp16 ws, chunked [icc][col=m*64+d][ck] (v7 layout) ----------
__global__ __launch_bounds__(256) void build_bk7(
    const float* __restrict__ kern, _Float16* __restrict__ bk)
{
    int e   = blockIdx.x * 256 + threadIdx.x;   // icc*16384 + col*32 + ck
    int ck  = e & 31;
    int col = (e >> 5) & 511;
    int icc = e >> 14;
    int i   = icc >> 1;
    int c   = (icc & 1) * 32 + ck;
    int m   = col >> 6;
    int d   = col & 63;
    bk[e] = (_Float16)kern[((i * NT + m) * CIN + c) * COUT + d];
}

// ---------- K0b: signal -> fp16 ----------
__global__ __launch_bounds__(256) void build_sig16(
    const float* __restrict__ signal, _Float16* __restrict__ sig16)
{
    int e = blockIdx.x * 256 + threadIdx.x;
    sig16[e] = (_Float16)signal[e];
}

// ---------- main v18 = v16 (267us) with gathers issued in PHASE2 ----------
// v16's bar1 drained freshly-issued sig/bary gathers with ~100cyc of cover,
// every iteration. Here phase1 issues NO vm ops (bar1 drains nothing new);
// the it+1 gathers are issued at the top of phase2 and ride under the
// MFMA block (~500-800cyc) before bar2's vmcnt(0) drain. Inventory = v16.
__global__ __launch_bounds__(512, 4) void geo_mfma18(
    const float* __restrict__ bary_w,
    const int*   __restrict__ bary_idx,
    const _Float16* __restrict__ sig16,
    const _Float16* __restrict__ bk,
    float* __restrict__ out,
    int*   __restrict__ wl)
{
    __shared__ __align__(16) _Float16 Blds[2][16384];   // 2 x 32 KB
    __shared__ __align__(16) _Float16 Axs[4][BM2][8];   // 4 KB (single-buf)
    __shared__ float nrm[BM2][NT];                      // 2 KB
    __shared__ int   besti[BM2];

    const int tid  = threadIdx.x;
    const int lane = tid & 63;
    const int wn   = tid >> 6;         // wave wn owns rotation k=wn
    const int g    = lane >> 4;
    const int l15  = lane & 15;
    const int vbase = blockIdx.x * BM2;

    // A-staging mapping: thread -> (vertex vt, ck-quad cq); 4 channels each
    const int vt = tid >> 3;
    const int cq = tid & 7;
    const int v_mine = vbase + vt;
    const bool v_ok = (v_mine < NV);

    f32x4 acc[4][4];
    {
        f32x4 z = {0.f, 0.f, 0.f, 0.f};
        #pragma unroll
        for (int mf = 0; mf < 4; ++mf)
            #pragma unroll
            for (int nf = 0; nf < 4; ++nf) acc[mf][nf] = z;
    }

    // iteration order: it = icc*8 + j  (icc outer, j inner)
    struct Gen { float w0, w1, w2; int i0, i1, i2; };
    auto LOADGEN = [&](int it2) -> Gen {
        Gen gg;
        const int itc = (it2 < NCH) ? it2 : (NCH - 1);
        const int icc2 = itc >> 3;
        const int j2   = itc & 7;
        const int i2   = icc2 >> 1;
        if (v_ok) {
            const int base = v_mine * BARY + (i2 * NT + j2) * 3;
            gg.w0 = bary_w[base + 0];
            gg.w1 = bary_w[base + 1];
            gg.w2 = bary_w[base + 2];
            gg.i0 = bary_idx[base + 0];
            gg.i1 = bary_idx[base + 1];
            gg.i2 = bary_idx[base + 2];
        } else {
            gg.w0 = gg.w1 = gg.w2 = 0.f;
            gg.i0 = gg.i1 = gg.i2 = 0;
        }
        return gg;
    };

    // sig slice: 4 ch at c = (icc&1)*32 + cq*4
    f16x4 sA0, sA1, sA2, sB0, sB1, sB2;
    auto SIGLOAD = [&](const Gen& gg, int it2, f16x4& o0, f16x4& o1, f16x4& o2) {
        const int itc = (it2 < NCH) ? it2 : (NCH - 1);
        const int icc2 = itc >> 3;
        const int coff = (icc2 & 1) * 32 + cq * 4;
        o0 = *(const f16x4*)(sig16 + gg.i0 * CIN + coff);
        o1 = *(const f16x4*)(sig16 + gg.i1 * CIN + coff);
        o2 = *(const f16x4*)(sig16 + gg.i2 * CIN + coff);
    };

    // B chunk reg-staging (once per icc)
    f16x8 breg0, breg1, breg2, breg3;
    auto BLOADR = [&](int icc2) {
        const _Float16* src = bk + icc2 * 16384 + wn * 2048 + lane * 8;
        breg0 = *(const f16x8*)(src + 0 * 512);
        breg1 = *(const f16x8*)(src + 1 * 512);
        breg2 = *(const f16x8*)(src + 2 * 512);
        breg3 = *(const f16x8*)(src + 3 * 512);
    };
    auto BWRITE = [&](int b) {
        _Float16* dst = &Blds[b][wn * 2048 + lane * 8];
        *(f16x8*)(dst + 0 * 512) = breg0;
        *(f16x8*)(dst + 1 * 512) = breg1;
        *(f16x8*)(dst + 2 * 512) = breg2;
        *(f16x8*)(dst + 3 * 512) = breg3;
    };

    // ---- prologue ----
    Gen g0 = LOADGEN(0);
    Gen g1 = LOADGEN(1);
    SIGLOAD(g0, 0, sA0, sA1, sA2);
    BLOADR(0);
    BWRITE(0);
    __syncthreads();

    int cur = 0;
    #pragma unroll 1
    for (int it = 0; it < NCH; ++it) {
        const int icc = it >> 3;
        const int j   = it & 7;
        const int m   = (j + wn) & 7;
        const bool stageB = (j == 7) && (icc + 1 < NICC);

        // ---- phase1: x(it) from regs -> Axs. NO new vm ops before bar1. ----
        {
            f16x4 hv;
            #pragma unroll
            for (int e = 0; e < 4; ++e) {
                float xf = g0.w0 * (float)sA0[e]
                         + g0.w1 * (float)sA1[e]
                         + g0.w2 * (float)sA2[e];
                hv[e] = (_Float16)xf;
            }
            *(f16x4*)&Axs[cq >> 1][vt][(cq & 1) * 4] = hv;
        }
        __syncthreads();   // bar1: Axs ready; nothing in vm queue -> cheap

        // ---- phase2: issue gathers + B first, MFMA covers them, then bar2 ----
        if (stageB) BLOADR(icc + 1);               // oldest in vm queue
        SIGLOAD(g1, it + 1, sB0, sB1, sB2);        // it+1 gathers ride under MFMAs
        Gen g2 = LOADGEN(it + 2);

        f16x8 afrag[4];
        #pragma unroll
        for (int mf = 0; mf < 4; ++mf)
            afrag[mf] = *(const f16x8*)&Axs[g][mf * 16 + l15][0];

        #pragma unroll
        for (int nf = 0; nf < 4; ++nf) {
            const int col = m * 64 + nf * 16 + l15;
            const f16x8 bfrag = *(const f16x8*)&Blds[cur][col * 32 + g * 8];
            #pragma unroll
            for (int mf = 0; mf < 4; ++mf)
                acc[mf][nf] = __builtin_amdgcn_mfma_f32_16x16x32_f16(
                    afrag[mf], bfrag, acc[mf][nf], 0, 0, 0);
        }

        if (stageB) BWRITE(cur ^ 1);   // counted vmcnt on breg (oldest), no drain
        __syncthreads();   // bar2: drains sig/gen (covered by MFMA phase)

        // rotate pipeline
        g0 = g1; g1 = g2;
        sA0 = sB0; sA1 = sB1; sA2 = sB2;
        if (j == 7) cur ^= 1;
    }

    // ---- epilogue: wave wn owns rotation wn; norms per row ----
    #pragma unroll
    for (int mf = 0; mf < 4; ++mf)
        #pragma unroll
        for (int ri = 0; ri < 4; ++ri) {
            float s = 0.f;
            #pragma unroll
            for (int nf = 0; nf < 4; ++nf) {
                float vv = acc[mf][nf][ri];
                s = fmaf(vv, vv, s);
            }
            #pragma unroll
            for (int off = 1; off < 16; off <<= 1)
                s += __shfl_xor(s, off);
            if (l15 == 0) nrm[mf * 16 + g * 4 + ri][wn] = s;
        }
    __syncthreads();

    if (tid < BM2) {
        const int v = vbase + tid;
        float bn = nrm[tid][0];
        float sec = -1e30f;
        int best = 0;
        #pragma unroll
        for (int k = 1; k < NT; ++k) {
            float nv = nrm[tid][k];
            if (nv > bn)       { sec = bn; bn = nv; best = k; }
            else if (nv > sec) { sec = nv; }
        }
        // gap-err sigma ~3.6e-3 -> ~8 sigma (validated rounds 14-22, absmax 0.0156)
        const bool flag = (bn - sec) <= (3.0e-2f + 4e-4f * bn);
        besti[tid] = flag ? -1 : best;
        if (flag && v < NV) { int p = atomicAdd(wl, 1); wl[1 + p] = v; }
    }
    __syncthreads();

    #pragma unroll
    for (int mf = 0; mf < 4; ++mf)
        #pragma unroll
        for (int ri = 0; ri < 4; ++ri) {
            const int row = mf * 16 + g * 4 + ri;
            const int v   = vbase + row;
            const int bsel = (v < NV) ? besti[row] : -1;
            if (bsel == wn) {
                #pragma unroll
                for (int nf = 0; nf < 4; ++nf) {
                    const int d = nf * 16 + l15;
                    out[v * COUT + d] = fmaxf(acc[mf][nf][ri], 0.0f);
                }
            }
        }
}

// ---------- parallel fp64 refine: one BLOCK (4 waves) per vertex ----------
__global__ __launch_bounds__(256) void geo_refine_f64p(
    const float* __restrict__ signal,
    const float* __restrict__ bary_w,
    const int*   __restrict__ bary_idx,
    const float* __restrict__ kern,
    float*       __restrict__ out,
    const int*   __restrict__ wl,
    int nall)
{
    __shared__ __align__(16) float xs[NR][CIN][NT];
    __shared__ double part[4][NT][COUT];
    __shared__ double convl[NT][COUT];
    __shared__ double nks[NT];
    __shared__ int bestS;

    const int tid  = threadIdx.x;
    const int wave = tid >> 6;
    const int lane = tid & 63;
    const int count = wl ? wl[0] : nall;

    for (int w = blockIdx.x; w < count; w += gridDim.x) {
        const int v = wl ? wl[1 + w] : w;

        for (int ij = wave; ij < NR * NT; ij += 4) {
            const int i = ij >> 3, j = ij & 7;
            const int base = v * BARY + ij * 3;
            const float w0 = bary_w[base], w1 = bary_w[base+1], w2 = bary_w[base+2];
            const int   i0 = bary_idx[base], i1 = bary_idx[base+1], i2 = bary_idx[base+2];
            xs[i][lane][j] = w0 * signal[i0*CIN + lane]
                           + w1 * signal[i1*CIN + lane]
                           + w2 * signal[i2*CIN + lane];
        }
        __syncthreads();

        double acc[NT];
        #pragma unroll
        for (int k = 0; k < NT; ++k) acc[k] = 0.0;

        for (int r = wave * 80; r < wave * 80 + 80; ++r) {
            const int i = r >> 6, c = r & 63;
            const float4 xa = *reinterpret_cast<const float4*>(&xs[i][c][0]);
            const float4 xb = *reinterpret_cast<const float4*>(&xs[i][c][4]);
            const double x8[NT] = {(double)xa.x, (double)xa.y, (double)xa.z, (double)xa.w,
                                   (double)xb.x, (double)xb.y, (double)xb.z, (double)xb.w};
            #pragma unroll
            for (int mm = 0; mm < NT; ++mm) {
                const double kv = (double)kern[((i * NT + mm) * CIN + c) * COUT + lane];
                #pragma unroll
                for (int k = 0; k < NT; ++k)
                    acc[k] = fma(x8[(mm - k + NT) & (NT - 1)], kv, acc[k]);
            }
        }
        #pragma unroll
        for (int k = 0; k < NT; ++k) part[wave][k][lane] = acc[k];
        __syncthreads();

        for (int kd = tid; kd < NT * COUT; kd += 256) {
            const int k = kd >> 6, d = kd & 63;
            convl[k][d] = ((part[0][k][d] + part[1][k][d])
                         + (part[2][k][d] + part[3][k][d]));
        }
        __syncthreads();

        for (int k = wave; k < NT; k += 4) {
            double n = convl[k][lane] * convl[k][lane];
            #pragma unroll
            for (int off = 32; off >= 1; off >>= 1) n += __shfl_xor(n, off);
            if (lane == 0) nks[k] = n;
        }
        __syncthreads();

        if (tid == 0) {
            int best = 0; double bn = nks[0];
            #pragma unroll
            for (int k = 1; k < NT; ++k)
                if (nks[k] > bn) { bn = nks[k]; best = k; }
            bestS = best;
        }
        __syncthreads();

        if (tid < COUT) out[v * COUT + tid] = fmaxf((float)convl[bestS][tid], 0.0f);
        __syncthreads();
    }
}

extern "C" void kernel_launch(void* const* d_in, const int* in_sizes, int n_in,
                              void* d_out, int out_size, void* d_ws, size_t ws_size,
                              hipStream_t stream) {
    const float* signal   = (const float*)d_in[0];
    const float* bary_w   = (const float*)d_in[1];
    const int*   bary_idx = (const int*)d_in[2];
    const float* kern     = (const float*)d_in[3];
    float* out = (float*)d_out;

    if (ws_size >= (size_t)WS_NEED7) {
        int* wl = (int*)d_ws;
        _Float16* bk    = (_Float16*)((char*)d_ws + WL_BYTES);
        _Float16* sig16 = (_Float16*)((char*)d_ws + WL_BYTES + 2u * BK_ELEMS);
        hipMemsetAsync(wl, 0, sizeof(int), stream);
        build_bk7<<<dim3(BK_ELEMS / 256), dim3(256), 0, stream>>>(kern, bk);
        build_sig16<<<dim3(NV * CIN / 256), dim3(256), 0, stream>>>(signal, sig16);
        geo_mfma18<<<dim3(NBLK2), dim3(512), 0, stream>>>(
            bary_w, bary_idx, sig16, bk, out, wl);
        geo_refine_f64p<<<dim3(1024), dim3(256), 0, stream>>>(
            signal, bary_w, bary_idx, kern, out, wl, 0);
    } else {
        geo_refine_f64p<<<dim3(1024), dim3(256), 0, stream>>>(
            signal, bary_w, bary_idx, kern, out, nullptr, NV);
    }
}